// Round 8
// baseline (159.954 us; speedup 1.0000x reference)
//
#include <hip/hip_runtime.h>

typedef _Float16 h2 __attribute__((ext_vector_type(2)));
typedef _Float16 h4 __attribute__((ext_vector_type(4)));
typedef _Float16 h8 __attribute__((ext_vector_type(8)));
typedef float    f4 __attribute__((ext_vector_type(4)));
typedef float    f16f __attribute__((ext_vector_type(16)));
typedef __fp16   fp16x2 __attribute__((ext_vector_type(2)));
typedef unsigned int u32x4 __attribute__((ext_vector_type(4)));

__device__ __forceinline__ unsigned cvt_pk_u32(float a, float b) {
    fp16x2 t = __builtin_amdgcn_cvt_pkrtz(a, b);
    return __builtin_bit_cast(unsigned, t);
}

// ---------------------------------------------------------------- helpers

__device__ __forceinline__ void gload_lds16(const void* g, void* l) {
    auto gp = reinterpret_cast<const __attribute__((address_space(1))) unsigned int*>(
        reinterpret_cast<uintptr_t>(g));
    auto lp = reinterpret_cast<__attribute__((address_space(3))) unsigned int*>(
        reinterpret_cast<uintptr_t>(l));
    __builtin_amdgcn_global_load_lds(gp, lp, 16, 0, 0);
}

// Stage ROWS x 64-half tile (global row-major, row stride gstride halfs) into LDS,
// split across NW waves. LDS linear; 16B units within each 128B row are
// XOR-swizzled on the GLOBAL side (rule #21).
template<int ROWS, int NW>
__device__ __forceinline__ void stage_swz(const _Float16* __restrict__ gbase, int gstride,
                                          _Float16* lbase)
{
    const int wid = threadIdx.x >> 6, lane = threadIdx.x & 63;
    constexpr int CHUNKS = ROWS * 8 / 64;   // 1KB chunks (64 lanes x 16B)
    #pragma unroll
    for (int c = 0; c < CHUNKS; c += NW) {
        int cc  = c + wid;
        int u   = cc * 64 + lane;           // 16B unit index
        int row = u >> 3, un = u & 7;
        const _Float16* src = gbase + (size_t)row * gstride + ((un ^ (row & 7)) << 3);
        gload_lds16(src, lbase + cc * 512); // wave-uniform base; HW adds lane*16
    }
}

// swizzled LDS reads: tile rows are 64 halfs (128B = 8 units)
__device__ __forceinline__ h8 lds_read8(const _Float16* base, int row, int col) {
    int off = row * 128 + ((((col >> 3) ^ (row & 7))) << 4);   // col % 8 == 0
    return *(const h8*)((const char*)base + off);
}

// ---------------------------------------------------------------- prep kernels

__global__ void convx_kernel(const float* __restrict__ x, _Float16* __restrict__ xh, int n8)
{
    int i = blockIdx.x * 256 + threadIdx.x;
    if (i >= n8) return;
    const f4* p = (const f4*)(x + (size_t)i * 8);
    f4 a = p[0], b = p[1];
    h8 o;
    #pragma unroll
    for (int j = 0; j < 4; ++j) { o[j] = (_Float16)a[j]; o[j+4] = (_Float16)b[j]; }
    *(h8*)(xh + (size_t)i * 8) = o;
}

// all three weight transposes in one dispatch; grid (64, 16)
__global__ void transw_all_kernel(const float* __restrict__ Wq, const float* __restrict__ Wkv,
                                  const float* __restrict__ Wo,
                                  _Float16* __restrict__ w1t, _Float16* __restrict__ w2t)
{
    __shared__ float tile[64][65];
    int bx = blockIdx.x;
    const float* src; _Float16* dst; int N, n0;
    if (bx < 16)      { src = Wq;  N = 1024; n0 = bx * 64;        dst = w1t; }
    else if (bx < 48) { src = Wkv; N = 2048; n0 = (bx - 16) * 64; dst = w1t + (size_t)1024 * 1024; }
    else              { src = Wo;  N = 1024; n0 = (bx - 48) * 64; dst = w2t; }
    int k0 = blockIdx.y * 64;
    int t = threadIdx.x;
    int tr = t >> 4, tc4 = (t & 15) * 4;
    #pragma unroll
    for (int i = 0; i < 4; ++i) {
        int r = tr + i * 16;
        f4 v = *(const f4*)(src + (size_t)(k0 + r) * N + n0 + tc4);
        tile[r][tc4 + 0] = v[0]; tile[r][tc4 + 1] = v[1];
        tile[r][tc4 + 2] = v[2]; tile[r][tc4 + 3] = v[3];
    }
    __syncthreads();
    #pragma unroll
    for (int i = 0; i < 4; ++i) {
        int r = tr + i * 16;                       // output row (n index)
        h4 ov;
        #pragma unroll
        for (int j = 0; j < 4; ++j) ov[j] = (_Float16)tile[tc4 + j][r];
        *(h4*)(dst + (size_t)(n0 + r) * 1024 + k0 + tc4) = ov;
    }
}

// in-place RoPE on q (cols 0..1023, scaled by 0.125*log2e for base-2 softmax)
// and k (cols 1024..2047); qkv stride 2048
__global__ void rope_kernel(_Float16* __restrict__ qkv,
                            const int* __restrict__ tq, const int* __restrict__ tk)
{
    int idx = blockIdx.x * 256 + threadIdx.x;          // 4096 rows * 256 groups
    int row = idx >> 8;
    int c8  = (idx & 255) << 3;                        // col 0..2047, 8 halfs
    bool isq = (c8 < 1024);
    int tv = isq ? tq[row] : tk[row];
    _Float16* p = qkv + (size_t)row * 2048 + c8;
    h8 v = *(const h8*)p;
    int p0 = (c8 & 63) >> 1;                           // pair index base (8|64: same head)
    float scale = isq ? 0.125f * 1.4426950408889634f : 1.0f; // fold softmax scale + log2e into q
    h8 ov;
    #pragma unroll
    for (int j = 0; j < 4; ++j) {
        // inv_freq = 10000^(-p/32) = 2^(-p*log2(10000)/32)
        float invf = exp2f(-(float)(p0 + j) * 0.41524101186092025f);
        float ang  = (float)tv * invf;
        float sv, cv; sincosf(ang, &sv, &cv);
        float x1 = (float)v[2 * j], x2 = (float)v[2 * j + 1];
        ov[2 * j]     = (_Float16)((x1 * cv - x2 * sv) * scale);
        ov[2 * j + 1] = (_Float16)((x1 * sv + x2 * cv) * scale);
    }
    *(h8*)p = ov;
}

// ---------------------------------------------------------------- GEMM
// C[M,N] = A[M,K] @ Bt[N,K]^T ; 128x128 tile, BK=64, 4 waves each 64x64.
// 2-phase double-buffer. CN = C row stride. If vtout != nullptr, blocks with
// n0 >= 2048 (the V projection) write TRANSPOSED to vt[bh][d][n] (fuses vtrans)
// and skip the C write.
template<bool OUT32>
__global__ __launch_bounds__(256) void gemm_kernel(
    const _Float16* __restrict__ A, const _Float16* __restrict__ Bt,
    void* __restrict__ Cout, const float* __restrict__ bias,
    _Float16* __restrict__ vtout,
    int M, int N, int K, int CN)
{
    __shared__ _Float16 Al[2 * 128 * 64];
    __shared__ _Float16 Bl[2 * 128 * 64];
    const int lane = threadIdx.x & 63, wid = threadIdx.x >> 6;
    const int wm = wid >> 1, wn = wid & 1;
    const int m0 = blockIdx.y * 128, n0 = blockIdx.x * 128;
    const int g = lane >> 4, c15 = lane & 15;
    f4 acc[4][4] = {};
    const int nkt = K >> 6;
    stage_swz<128, 4>(A  + (size_t)m0 * K, K, Al);
    stage_swz<128, 4>(Bt + (size_t)n0 * K, K, Bl);
    __syncthreads();
    for (int kt = 0; kt < nkt; ++kt) {
        const int cur = kt & 1;
        _Float16* Ac = Al + cur * 8192;
        _Float16* Bc = Bl + cur * 8192;
        if (kt + 1 < nkt) {
            stage_swz<128, 4>(A  + (size_t)m0 * K + (kt + 1) * 64, K, Al + (cur ^ 1) * 8192);
            stage_swz<128, 4>(Bt + (size_t)n0 * K + (kt + 1) * 64, K, Bl + (cur ^ 1) * 8192);
        }
        #pragma unroll
        for (int ks = 0; ks < 2; ++ks) {
            const int kc = ks * 32 + g * 8;
            h8 a[4], b[4];
            #pragma unroll
            for (int mi = 0; mi < 4; ++mi) a[mi] = lds_read8(Ac, wm * 64 + mi * 16 + c15, kc);
            #pragma unroll
            for (int ni = 0; ni < 4; ++ni) b[ni] = lds_read8(Bc, wn * 64 + ni * 16 + c15, kc);
            #pragma unroll
            for (int mi = 0; mi < 4; ++mi)
                #pragma unroll
                for (int ni = 0; ni < 4; ++ni)
                    acc[mi][ni] = __builtin_amdgcn_mfma_f32_16x16x32_f16(
                        a[mi], b[ni], acc[mi][ni], 0, 0, 0);
        }
        __syncthreads();
    }
    const bool vpath = (!OUT32) && (vtout != nullptr) && (n0 >= 2048);
    #pragma unroll
    for (int mi = 0; mi < 4; ++mi) {
        #pragma unroll
        for (int ni = 0; ni < 4; ++ni) {
            int row0 = m0 + wm * 64 + mi * 16 + g * 4;
            int col  = n0 + wn * 64 + ni * 16 + c15;
            if (OUT32) {
                float bv = bias ? bias[col] : 0.f;
                float* C = (float*)Cout;
                #pragma unroll
                for (int r = 0; r < 4; ++r)
                    C[(size_t)(row0 + r) * CN + col] = acc[mi][ni][r] + bv;
            } else if (vpath) {
                int cv = col - 2048;
                int hh = cv >> 6, dd = cv & 63;
                int bb = row0 >> 11, nn = row0 & 2047;
                h4 ov;
                #pragma unroll
                for (int r = 0; r < 4; ++r) ov[r] = (_Float16)acc[mi][ni][r];
                *(h4*)(vtout + (size_t)((bb * 16 + hh) * 64 + dd) * 2048 + nn) = ov;
            } else {
                _Float16* C = (_Float16*)Cout;
                #pragma unroll
                for (int r = 0; r < 4; ++r)
                    C[(size_t)(row0 + r) * CN + col] = (_Float16)acc[mi][ni][r];
            }
        }
    }
}

// ---------------------------------------------------------------- flash attention
// grid (16 q-tiles, 32 bh, 2 kv-splits); 4 waves, each 32 q-rows; KVBLK=64, dbuf.
// Each split covers 1024 kv (16 iters), writes l-normalized fp16 partial O + (m,l).
// 32x32x16 MFMA, swapped QK^T (q = lane&31 lane-local), T12 P->B-frag assembly,
// base-2 softmax, defer-max THR=8, tree-shaped max/denom reductions.
__global__ __launch_bounds__(256) void attn_kernel(
    const _Float16* __restrict__ qkv, const _Float16* __restrict__ vt,
    _Float16* __restrict__ po, float* __restrict__ ml)
{
    // halfs: K0 [0,4096) | K1 [4096,8192) | V0 [8192,12288) | V1 [12288,16384)
    __shared__ _Float16 smem[16384];                   // 32 KB
    const int lane = threadIdx.x & 63, wid = threadIdx.x >> 6;
    const int q32 = lane & 31, h = lane >> 5;
    const int qt = blockIdx.x, bh = blockIdx.y, z = blockIdx.z;
    const int b = bh >> 4, hh = bh & 15;
    const int q0 = qt * 128;
    const int kv0 = z * 1024;

    const _Float16* Kg = qkv + (size_t)(b * 2048 + kv0) * 2048 + 1024 + hh * 64;
    const _Float16* Vg = vt + (size_t)bh * 64 * 2048 + kv0;

    // staging: 4 waves x 2 chunks each per tile (chunks wid, wid+4)
    const int srow = wid * 8 + (lane >> 3);
    const int sswz = ((lane & 7) ^ (srow & 7)) << 3;
    const _Float16* kst  = Kg + (size_t)srow * 2048 + sswz;
    const _Float16* kst2 = kst + (size_t)32 * 2048;
    const _Float16* vst  = Vg + (size_t)srow * 2048 + sswz;
    const _Float16* vst2 = vst + (size_t)32 * 2048;

    // prologue: stage tile 0 into buf 0
    gload_lds16(kst,  smem + wid * 512);
    gload_lds16(kst2, smem + (wid + 4) * 512);
    gload_lds16(vst,  smem + 8192 + wid * 512);
    gload_lds16(vst2, smem + 8192 + (wid + 4) * 512);
    kst += 64 * 2048; kst2 += 64 * 2048; vst += 64; vst2 += 64;

    // Q -> regs: B-frag [k=16 d][n=32 q]: n=q32, k = ds*16 + h*8 + j
    const int qrow = q0 + wid * 32 + q32;
    const _Float16* Qg = qkv + (size_t)(b * 2048 + qrow) * 2048 + hh * 64 + h * 8;
    h8 qf[4];
    #pragma unroll
    for (int ds = 0; ds < 4; ++ds) qf[ds] = *(const h8*)(Qg + ds * 16);

    // LDS read byte bases: row r = q32 (+32 via +4096), unit = (i*2+h) ^ (r&7)
    const char* sb = (const char*)smem;
    const int r7 = q32 & 7;
    int bk[4], bv[4];
    #pragma unroll
    for (int i = 0; i < 4; ++i) {
        bk[i] = q32 * 128 + (((i * 2 + h) ^ r7) << 4);
        bv[i] = 16384 + q32 * 128 + (((i * 2 + h) ^ r7) << 4);
    }

    __syncthreads();

    f16f o0 = {}, o1 = {};
    f4 dacc4 = {};
    float m_run = -1e30f;

#define MAKE_PA(SV, PA_A, PA_B)                                                      \
    {                                                                                \
        float e[16];                                                                 \
        _Pragma("unroll")                                                            \
        for (int r = 0; r < 16; ++r) { e[r] = exp2f(SV[r] - m_run);                  \
                                       dacc4[r & 3] += e[r]; }                       \
        unsigned wA = cvt_pk_u32(e[0], e[1]), wB = cvt_pk_u32(e[2], e[3]);           \
        unsigned wC = cvt_pk_u32(e[4], e[5]), wD = cvt_pk_u32(e[6], e[7]);           \
        asm volatile("v_permlane32_swap_b32 %0, %1" : "+v"(wA), "+v"(wC));           \
        asm volatile("v_permlane32_swap_b32 %0, %1" : "+v"(wB), "+v"(wD));           \
        u32x4 ta = {wA, wB, wC, wD};                                                 \
        PA_A = __builtin_bit_cast(h8, ta);                                           \
        unsigned xA = cvt_pk_u32(e[8], e[9]),  xB = cvt_pk_u32(e[10], e[11]);        \
        unsigned xC = cvt_pk_u32(e[12], e[13]), xD = cvt_pk_u32(e[14], e[15]);       \
        asm volatile("v_permlane32_swap_b32 %0, %1" : "+v"(xA), "+v"(xC));           \
        asm volatile("v_permlane32_swap_b32 %0, %1" : "+v"(xB), "+v"(xD));           \
        u32x4 tb = {xA, xB, xC, xD};                                                 \
        PA_B = __builtin_bit_cast(h8, tb);                                           \
    }

#define ATT_ITER(CUR, TT)                                                            \
    {                                                                                \
        constexpr int cur = (CUR);                                                   \
        const int tt = (TT);                                                         \
        if (tt + 1 < 16) {                                                           \
            gload_lds16(kst,  smem + (cur ^ 1) * 4096 + wid * 512);                  \
            gload_lds16(kst2, smem + (cur ^ 1) * 4096 + (wid + 4) * 512);            \
            gload_lds16(vst,  smem + 8192 + (cur ^ 1) * 4096 + wid * 512);           \
            gload_lds16(vst2, smem + 8192 + (cur ^ 1) * 4096 + (wid + 4) * 512);     \
            kst += 64 * 2048; kst2 += 64 * 2048; vst += 64; vst2 += 64;              \
        }                                                                            \
        f16f s0 = {}, s1 = {};                                                       \
        __builtin_amdgcn_s_setprio(1);                                               \
        _Pragma("unroll")                                                            \
        for (int ds = 0; ds < 4; ++ds) {                                             \
            h8 klo = *(const h8*)(sb + bk[ds] + cur * 8192);                         \
            h8 khi = *(const h8*)(sb + bk[ds] + cur * 8192 + 4096);                  \
            s0 = __builtin_amdgcn_mfma_f32_32x32x16_f16(klo, qf[ds], s0, 0, 0, 0);   \
            s1 = __builtin_amdgcn_mfma_f32_32x32x16_f16(khi, qf[ds], s1, 0, 0, 0);   \
        }                                                                            \
        __builtin_amdgcn_s_setprio(0);                                               \
        float a[16];                                                                 \
        _Pragma("unroll")                                                            \
        for (int r = 0; r < 16; ++r) a[r] = fmaxf(s0[r], s1[r]);                     \
        _Pragma("unroll")                                                            \
        for (int st = 8; st >= 1; st >>= 1)                                          \
            _Pragma("unroll")                                                        \
            for (int i = 0; i < 8; ++i) if (i < st) a[i] = fmaxf(a[i], a[i + st]);   \
        float mx = fmaxf(a[0], __shfl_xor(a[0], 32));                                \
        if (!__all(mx <= m_run + 8.0f)) {                                            \
            float mnew = fmaxf(m_run, mx);                                           \
            float corr = exp2f(m_run - mnew);                                        \
            m_run = mnew;                                                            \
            dacc4 *= corr;                                                           \
            o0 *= corr; o1 *= corr;                                                  \
        }                                                                            \
        h8 pa0, pa1, pa2, pa3;                                                       \
        MAKE_PA(s0, pa0, pa1)                                                        \
        MAKE_PA(s1, pa2, pa3)                                                        \
        __builtin_amdgcn_s_setprio(1);                                               \
        _Pragma("unroll")                                                            \
        for (int ks = 0; ks < 4; ++ks) {                                             \
            h8 pb = (ks == 0) ? pa0 : (ks == 1) ? pa1 : (ks == 2) ? pa2 : pa3;       \
            h8 vlo = *(const h8*)(sb + bv[ks] + cur * 8192);                         \
            h8 vhi = *(const h8*)(sb + bv[ks] + cur * 8192 + 4096);                  \
            o0 = __builtin_amdgcn_mfma_f32_32x32x16_f16(vlo, pb, o0, 0, 0, 0);       \
            o1 = __builtin_amdgcn_mfma_f32_32x32x16_f16(vhi, pb, o1, 0, 0, 0);       \
        }                                                                            \
        __builtin_amdgcn_s_setprio(0);                                               \
        __syncthreads();                                                             \
    }

    for (int t2 = 0; t2 < 8; ++t2) {
        ATT_ITER(0, 2 * t2)
        ATT_ITER(1, 2 * t2 + 1)
    }
#undef ATT_ITER
#undef MAKE_PA

    float l_loc = (dacc4[0] + dacc4[1]) + (dacc4[2] + dacc4[3]);
    float l_tot = l_loc + __shfl_xor(l_loc, 32);
    float inv_l = 1.f / l_tot;

    const int prow = (z * 32 + bh) * 2048 + qrow;       // partial row index
    _Float16* pop = po + (size_t)prow * 64 + 4 * h;
    #pragma unroll
    for (int w = 0; w < 4; ++w) {
        h4 ov;
        #pragma unroll
        for (int r = 0; r < 4; ++r) ov[r] = (_Float16)(o0[w * 4 + r] * inv_l);
        *(h4*)(pop + w * 8) = ov;
    }
    #pragma unroll
    for (int w = 0; w < 4; ++w) {
        h4 ov;
        #pragma unroll
        for (int r = 0; r < 4; ++r) ov[r] = (_Float16)(o1[w * 4 + r] * inv_l);
        *(h4*)(pop + 32 + w * 8) = ov;
    }
    if (h == 0) {                                       // lanes 0..31: one q-row each
        ml[(size_t)prow * 2]     = m_run;
        ml[(size_t)prow * 2 + 1] = l_tot;
    }
}

// merge the two kv-split partials: ao = w1*po1 + w2*po2
__global__ void combine_kernel(const _Float16* __restrict__ po, const float* __restrict__ ml,
                               _Float16* __restrict__ ao)
{
    int u = blockIdx.x * 256 + threadIdx.x;            // 524288 = 4096*16*8
    int pair = u >> 3, d8 = (u & 7) * 8;
    int qg = pair >> 4, hh = pair & 15;                // qg = b*2048+qrow
    int b = qg >> 11, qrow = qg & 2047;
    int r = (b * 16 + hh) * 2048 + qrow;
    float m1 = ml[(size_t)r * 2],           l1 = ml[(size_t)r * 2 + 1];
    float m2 = ml[131072 + (size_t)r * 2],  l2 = ml[131072 + (size_t)r * 2 + 1];
    float ms = fmaxf(m1, m2);
    float w1 = exp2f(m1 - ms) * l1, w2 = exp2f(m2 - ms) * l2;
    float inv = 1.f / (w1 + w2);
    w1 *= inv; w2 *= inv;
    h8 v1 = *(const h8*)(po + (size_t)r * 64 + d8);
    h8 v2 = *(const h8*)(po + 4194304 + (size_t)r * 64 + d8);
    h8 o;
    #pragma unroll
    for (int j = 0; j < 8; ++j) o[j] = (_Float16)((float)v1[j] * w1 + (float)v2[j] * w2);
    *(h8*)(ao + (size_t)qg * 1024 + hh * 64 + d8) = o;
}

// ---------------------------------------------------------------- launch

extern "C" void kernel_launch(void* const* d_in, const int* in_sizes, int n_in,
                              void* d_out, int out_size, void* d_ws, size_t ws_size,
                              hipStream_t stream) {
    const float* x   = (const float*)d_in[0];
    const int*   tq  = (const int*)d_in[1];
    const int*   tk  = (const int*)d_in[2];
    const float* Wq  = (const float*)d_in[3];
    const float* Wkv = (const float*)d_in[4];
    const float* Wo  = (const float*)d_in[5];
    const float* bo  = (const float*)d_in[6];
    float* out = (float*)d_out;

    char* ws = (char*)d_ws;
    _Float16* xh  = (_Float16*)(ws);                    //  8 MB [4096][1024]
    _Float16* w1t = (_Float16*)(ws + 8388608);          //  6 MB [3072][1024]
    _Float16* w2t = (_Float16*)(ws + 14680064);         //  2 MB [1024][1024]
    _Float16* qkv = (_Float16*)(ws + 16777216);         // 16 MB [4096][2048] (q|k)
    _Float16* vt  = (_Float16*)(ws + 33554432);         //  8 MB [32 bh][64 d][2048 n]
    _Float16* ao  = (_Float16*)(ws + 41943040);         //  8 MB [4096][1024]
    _Float16* po  = (_Float16*)(ws + 50331648);         // 16 MB [2][32 bh][2048][64]
    float*    ml  = (float*)   (ws + 67108864);         //  2 MB [2][32 bh][2048][2]

    convx_kernel<<<2048, 256, 0, stream>>>(x, xh, 524288);
    transw_all_kernel<<<dim3(64, 16), 256, 0, stream>>>(Wq, Wkv, Wo, w1t, w2t);

    gemm_kernel<false><<<dim3(24, 32), 256, 0, stream>>>(xh, w1t, qkv, nullptr, vt,
                                                         4096, 3072, 1024, 2048);

    rope_kernel<<<4096, 256, 0, stream>>>(qkv, tq, tk);

    attn_kernel<<<dim3(16, 32, 2), 256, 0, stream>>>(qkv, vt, po, ml);
    combine_kernel<<<2048, 256, 0, stream>>>(po, ml, ao);

    gemm_kernel<true><<<dim3(8, 32), 256, 0, stream>>>(ao, w2t, out, bo, nullptr,
                                                       4096, 1024, 1024, 1024);
}

// Round 9
// 138.930 us; speedup vs baseline: 1.1513x; 1.1513x over previous
//
#include <hip/hip_runtime.h>

typedef _Float16 h2 __attribute__((ext_vector_type(2)));
typedef _Float16 h4 __attribute__((ext_vector_type(4)));
typedef _Float16 h8 __attribute__((ext_vector_type(8)));
typedef float    f4 __attribute__((ext_vector_type(4)));
typedef float    f16f __attribute__((ext_vector_type(16)));
typedef __fp16   fp16x2 __attribute__((ext_vector_type(2)));
typedef unsigned int u32x4 __attribute__((ext_vector_type(4)));

__device__ __forceinline__ unsigned cvt_pk_u32(float a, float b) {
    fp16x2 t = __builtin_amdgcn_cvt_pkrtz(a, b);
    return __builtin_bit_cast(unsigned, t);
}

// ---------------------------------------------------------------- helpers

__device__ __forceinline__ void gload_lds16(const void* g, void* l) {
    auto gp = reinterpret_cast<const __attribute__((address_space(1))) unsigned int*>(
        reinterpret_cast<uintptr_t>(g));
    auto lp = reinterpret_cast<__attribute__((address_space(3))) unsigned int*>(
        reinterpret_cast<uintptr_t>(l));
    __builtin_amdgcn_global_load_lds(gp, lp, 16, 0, 0);
}

// Stage ROWS x 64-half tile (global row-major, row stride gstride halfs) into LDS,
// split across NW waves. LDS linear; 16B units within each 128B row are
// XOR-swizzled on the GLOBAL side (rule #21).
template<int ROWS, int NW>
__device__ __forceinline__ void stage_swz(const _Float16* __restrict__ gbase, int gstride,
                                          _Float16* lbase)
{
    const int wid = threadIdx.x >> 6, lane = threadIdx.x & 63;
    constexpr int CHUNKS = ROWS * 8 / 64;   // 1KB chunks (64 lanes x 16B)
    #pragma unroll
    for (int c = 0; c < CHUNKS; c += NW) {
        int cc  = c + wid;
        int u   = cc * 64 + lane;           // 16B unit index
        int row = u >> 3, un = u & 7;
        const _Float16* src = gbase + (size_t)row * gstride + ((un ^ (row & 7)) << 3);
        gload_lds16(src, lbase + cc * 512); // wave-uniform base; HW adds lane*16
    }
}

// swizzled LDS reads: tile rows are 64 halfs (128B = 8 units)
__device__ __forceinline__ h8 lds_read8(const _Float16* base, int row, int col) {
    int off = row * 128 + ((((col >> 3) ^ (row & 7))) << 4);   // col % 8 == 0
    return *(const h8*)((const char*)base + off);
}

// ---------------------------------------------------------------- prep kernels

__global__ void convx_kernel(const float* __restrict__ x, _Float16* __restrict__ xh, int n8)
{
    int i = blockIdx.x * 256 + threadIdx.x;
    if (i >= n8) return;
    const f4* p = (const f4*)(x + (size_t)i * 8);
    f4 a = p[0], b = p[1];
    h8 o;
    #pragma unroll
    for (int j = 0; j < 4; ++j) { o[j] = (_Float16)a[j]; o[j+4] = (_Float16)b[j]; }
    *(h8*)(xh + (size_t)i * 8) = o;
}

// all three weight transposes in one dispatch; grid (64, 16)
__global__ void transw_all_kernel(const float* __restrict__ Wq, const float* __restrict__ Wkv,
                                  const float* __restrict__ Wo,
                                  _Float16* __restrict__ w1t, _Float16* __restrict__ w2t)
{
    __shared__ float tile[64][65];
    int bx = blockIdx.x;
    const float* src; _Float16* dst; int N, n0;
    if (bx < 16)      { src = Wq;  N = 1024; n0 = bx * 64;        dst = w1t; }
    else if (bx < 48) { src = Wkv; N = 2048; n0 = (bx - 16) * 64; dst = w1t + (size_t)1024 * 1024; }
    else              { src = Wo;  N = 1024; n0 = (bx - 48) * 64; dst = w2t; }
    int k0 = blockIdx.y * 64;
    int t = threadIdx.x;
    int tr = t >> 4, tc4 = (t & 15) * 4;
    #pragma unroll
    for (int i = 0; i < 4; ++i) {
        int r = tr + i * 16;
        f4 v = *(const f4*)(src + (size_t)(k0 + r) * N + n0 + tc4);
        tile[r][tc4 + 0] = v[0]; tile[r][tc4 + 1] = v[1];
        tile[r][tc4 + 2] = v[2]; tile[r][tc4 + 3] = v[3];
    }
    __syncthreads();
    #pragma unroll
    for (int i = 0; i < 4; ++i) {
        int r = tr + i * 16;                       // output row (n index)
        h4 ov;
        #pragma unroll
        for (int j = 0; j < 4; ++j) ov[j] = (_Float16)tile[tc4 + j][r];
        *(h4*)(dst + (size_t)(n0 + r) * 1024 + k0 + tc4) = ov;
    }
}

// in-place RoPE on q (cols 0..1023, scaled by 0.125*log2e for base-2 softmax)
// and k (cols 1024..2047); qkv stride 2048. libm sincosf kept deliberately:
// matches the reference's f32 trig rounding.
__global__ void rope_kernel(_Float16* __restrict__ qkv,
                            const int* __restrict__ tq, const int* __restrict__ tk)
{
    int idx = blockIdx.x * 256 + threadIdx.x;          // 4096 rows * 256 groups
    int row = idx >> 8;
    int c8  = (idx & 255) << 3;                        // col 0..2047, 8 halfs
    bool isq = (c8 < 1024);
    int tv = isq ? tq[row] : tk[row];
    _Float16* p = qkv + (size_t)row * 2048 + c8;
    h8 v = *(const h8*)p;
    int p0 = (c8 & 63) >> 1;                           // pair index base (8|64: same head)
    float scale = isq ? 0.125f * 1.4426950408889634f : 1.0f; // fold softmax scale + log2e into q
    h8 ov;
    #pragma unroll
    for (int j = 0; j < 4; ++j) {
        // inv_freq = 10000^(-p/32) = 2^(-p*log2(10000)/32)
        float invf = exp2f(-(float)(p0 + j) * 0.41524101186092025f);
        float ang  = (float)tv * invf;
        float sv, cv; sincosf(ang, &sv, &cv);
        float x1 = (float)v[2 * j], x2 = (float)v[2 * j + 1];
        ov[2 * j]     = (_Float16)((x1 * cv - x2 * sv) * scale);
        ov[2 * j + 1] = (_Float16)((x1 * sv + x2 * cv) * scale);
    }
    *(h8*)p = ov;
}

// ---------------------------------------------------------------- GEMM
// C[M,N] = A[M,K] @ Bt[N,K]^T ; 128x128 tile, BK=64, 4 waves each 64x64.
// 2-phase double-buffer. CN = C row stride. If vtout != nullptr, blocks with
// n0 >= 2048 (the V projection) write TRANSPOSED to vt[bh][d][n] (fuses vtrans)
// and skip the C write.
template<bool OUT32>
__global__ __launch_bounds__(256) void gemm_kernel(
    const _Float16* __restrict__ A, const _Float16* __restrict__ Bt,
    void* __restrict__ Cout, const float* __restrict__ bias,
    _Float16* __restrict__ vtout,
    int M, int N, int K, int CN)
{
    __shared__ _Float16 Al[2 * 128 * 64];
    __shared__ _Float16 Bl[2 * 128 * 64];
    const int lane = threadIdx.x & 63, wid = threadIdx.x >> 6;
    const int wm = wid >> 1, wn = wid & 1;
    const int m0 = blockIdx.y * 128, n0 = blockIdx.x * 128;
    const int g = lane >> 4, c15 = lane & 15;
    f4 acc[4][4] = {};
    const int nkt = K >> 6;
    stage_swz<128, 4>(A  + (size_t)m0 * K, K, Al);
    stage_swz<128, 4>(Bt + (size_t)n0 * K, K, Bl);
    __syncthreads();
    for (int kt = 0; kt < nkt; ++kt) {
        const int cur = kt & 1;
        _Float16* Ac = Al + cur * 8192;
        _Float16* Bc = Bl + cur * 8192;
        if (kt + 1 < nkt) {
            stage_swz<128, 4>(A  + (size_t)m0 * K + (kt + 1) * 64, K, Al + (cur ^ 1) * 8192);
            stage_swz<128, 4>(Bt + (size_t)n0 * K + (kt + 1) * 64, K, Bl + (cur ^ 1) * 8192);
        }
        #pragma unroll
        for (int ks = 0; ks < 2; ++ks) {
            const int kc = ks * 32 + g * 8;
            h8 a[4], b[4];
            #pragma unroll
            for (int mi = 0; mi < 4; ++mi) a[mi] = lds_read8(Ac, wm * 64 + mi * 16 + c15, kc);
            #pragma unroll
            for (int ni = 0; ni < 4; ++ni) b[ni] = lds_read8(Bc, wn * 64 + ni * 16 + c15, kc);
            #pragma unroll
            for (int mi = 0; mi < 4; ++mi)
                #pragma unroll
                for (int ni = 0; ni < 4; ++ni)
                    acc[mi][ni] = __builtin_amdgcn_mfma_f32_16x16x32_f16(
                        a[mi], b[ni], acc[mi][ni], 0, 0, 0);
        }
        __syncthreads();
    }
    const bool vpath = (!OUT32) && (vtout != nullptr) && (n0 >= 2048);
    #pragma unroll
    for (int mi = 0; mi < 4; ++mi) {
        #pragma unroll
        for (int ni = 0; ni < 4; ++ni) {
            int row0 = m0 + wm * 64 + mi * 16 + g * 4;
            int col  = n0 + wn * 64 + ni * 16 + c15;
            if (OUT32) {
                float bv = bias ? bias[col] : 0.f;
                float* C = (float*)Cout;
                #pragma unroll
                for (int r = 0; r < 4; ++r)
                    C[(size_t)(row0 + r) * CN + col] = acc[mi][ni][r] + bv;
            } else if (vpath) {
                int cv = col - 2048;
                int hh = cv >> 6, dd = cv & 63;
                int bb = row0 >> 11, nn = row0 & 2047;
                h4 ov;
                #pragma unroll
                for (int r = 0; r < 4; ++r) ov[r] = (_Float16)acc[mi][ni][r];
                *(h4*)(vtout + (size_t)((bb * 16 + hh) * 64 + dd) * 2048 + nn) = ov;
            } else {
                _Float16* C = (_Float16*)Cout;
                #pragma unroll
                for (int r = 0; r < 4; ++r)
                    C[(size_t)(row0 + r) * CN + col] = (_Float16)acc[mi][ni][r];
            }
        }
    }
}

// ---------------------------------------------------------------- flash attention
// grid (16 q-tiles, 32 bh); 4 waves, each 32 q-rows (QBLK=128); KVBLK=64, dbuf.
// 32x32x16 MFMA, swapped QK^T (q = lane&31 lane-local), T12 P->B-frag assembly,
// base-2 softmax with NATIVE v_exp_f32, defer-max THR=8, tree reductions.
__global__ __launch_bounds__(256) void attn_kernel(
    const _Float16* __restrict__ qkv, const _Float16* __restrict__ vt,
    _Float16* __restrict__ ao)
{
    // halfs: K0 [0,4096) | K1 [4096,8192) | V0 [8192,12288) | V1 [12288,16384)
    __shared__ _Float16 smem[16384];                   // 32 KB
    const int lane = threadIdx.x & 63, wid = threadIdx.x >> 6;
    const int q32 = lane & 31, h = lane >> 5;
    const int qt = blockIdx.x, bh = blockIdx.y;
    const int b = bh >> 4, hh = bh & 15;
    const int q0 = qt * 128;

    const _Float16* Kg = qkv + (size_t)(b * 2048) * 2048 + 1024 + hh * 64;
    const _Float16* Vg = vt + (size_t)bh * 64 * 2048;

    // staging: 4 waves x 2 chunks each per tile (chunks wid, wid+4)
    const int srow = wid * 8 + (lane >> 3);
    const int sswz = ((lane & 7) ^ (srow & 7)) << 3;
    const _Float16* kst  = Kg + (size_t)srow * 2048 + sswz;
    const _Float16* kst2 = kst + (size_t)32 * 2048;
    const _Float16* vst  = Vg + (size_t)srow * 2048 + sswz;
    const _Float16* vst2 = vst + (size_t)32 * 2048;

    // prologue: stage tile 0 into buf 0
    gload_lds16(kst,  smem + wid * 512);
    gload_lds16(kst2, smem + (wid + 4) * 512);
    gload_lds16(vst,  smem + 8192 + wid * 512);
    gload_lds16(vst2, smem + 8192 + (wid + 4) * 512);
    kst += 64 * 2048; kst2 += 64 * 2048; vst += 64; vst2 += 64;

    // Q -> regs: B-frag [k=16 d][n=32 q]: n=q32, k = ds*16 + h*8 + j
    const int qrow = q0 + wid * 32 + q32;
    const _Float16* Qg = qkv + (size_t)(b * 2048 + qrow) * 2048 + hh * 64 + h * 8;
    h8 qf[4];
    #pragma unroll
    for (int ds = 0; ds < 4; ++ds) qf[ds] = *(const h8*)(Qg + ds * 16);

    // LDS read byte bases: row r = q32 (+32 via +4096), unit = (i*2+h) ^ (r&7)
    const char* sb = (const char*)smem;
    const int r7 = q32 & 7;
    int bk[4], bv[4];
    #pragma unroll
    for (int i = 0; i < 4; ++i) {
        bk[i] = q32 * 128 + (((i * 2 + h) ^ r7) << 4);
        bv[i] = 16384 + q32 * 128 + (((i * 2 + h) ^ r7) << 4);
    }

    __syncthreads();

    f16f o0 = {}, o1 = {};
    f4 dacc4 = {};
    float m_run = -1e30f;

#define MAKE_PA(SV, PA_A, PA_B)                                                      \
    {                                                                                \
        float e[16];                                                                 \
        _Pragma("unroll")                                                            \
        for (int r = 0; r < 16; ++r) { e[r] = __builtin_amdgcn_exp2f(SV[r] - m_run); \
                                       dacc4[r & 3] += e[r]; }                       \
        unsigned wA = cvt_pk_u32(e[0], e[1]), wB = cvt_pk_u32(e[2], e[3]);           \
        unsigned wC = cvt_pk_u32(e[4], e[5]), wD = cvt_pk_u32(e[6], e[7]);           \
        asm volatile("v_permlane32_swap_b32 %0, %1" : "+v"(wA), "+v"(wC));           \
        asm volatile("v_permlane32_swap_b32 %0, %1" : "+v"(wB), "+v"(wD));           \
        u32x4 ta = {wA, wB, wC, wD};                                                 \
        PA_A = __builtin_bit_cast(h8, ta);                                           \
        unsigned xA = cvt_pk_u32(e[8], e[9]),  xB = cvt_pk_u32(e[10], e[11]);        \
        unsigned xC = cvt_pk_u32(e[12], e[13]), xD = cvt_pk_u32(e[14], e[15]);       \
        asm volatile("v_permlane32_swap_b32 %0, %1" : "+v"(xA), "+v"(xC));           \
        asm volatile("v_permlane32_swap_b32 %0, %1" : "+v"(xB), "+v"(xD));           \
        u32x4 tb = {xA, xB, xC, xD};                                                 \
        PA_B = __builtin_bit_cast(h8, tb);                                           \
    }

#define ATT_ITER(CUR, TT)                                                            \
    {                                                                                \
        constexpr int cur = (CUR);                                                   \
        const int tt = (TT);                                                         \
        if (tt + 1 < 32) {                                                           \
            gload_lds16(kst,  smem + (cur ^ 1) * 4096 + wid * 512);                  \
            gload_lds16(kst2, smem + (cur ^ 1) * 4096 + (wid + 4) * 512);            \
            gload_lds16(vst,  smem + 8192 + (cur ^ 1) * 4096 + wid * 512);           \
            gload_lds16(vst2, smem + 8192 + (cur ^ 1) * 4096 + (wid + 4) * 512);     \
            kst += 64 * 2048; kst2 += 64 * 2048; vst += 64; vst2 += 64;              \
        }                                                                            \
        f16f s0 = {}, s1 = {};                                                       \
        __builtin_amdgcn_s_setprio(1);                                               \
        _Pragma("unroll")                                                            \
        for (int ds = 0; ds < 4; ++ds) {                                             \
            h8 klo = *(const h8*)(sb + bk[ds] + cur * 8192);                         \
            h8 khi = *(const h8*)(sb + bk[ds] + cur * 8192 + 4096);                  \
            s0 = __builtin_amdgcn_mfma_f32_32x32x16_f16(klo, qf[ds], s0, 0, 0, 0);   \
            s1 = __builtin_amdgcn_mfma_f32_32x32x16_f16(khi, qf[ds], s1, 0, 0, 0);   \
        }                                                                            \
        __builtin_amdgcn_s_setprio(0);                                               \
        float a[16];                                                                 \
        _Pragma("unroll")                                                            \
        for (int r = 0; r < 16; ++r) a[r] = fmaxf(s0[r], s1[r]);                     \
        _Pragma("unroll")                                                            \
        for (int st = 8; st >= 1; st >>= 1)                                          \
            _Pragma("unroll")                                                        \
            for (int i = 0; i < 8; ++i) if (i < st) a[i] = fmaxf(a[i], a[i + st]);   \
        float mx = fmaxf(a[0], __shfl_xor(a[0], 32));                                \
        if (!__all(mx <= m_run + 8.0f)) {                                            \
            float mnew = fmaxf(m_run, mx);                                           \
            float corr = __builtin_amdgcn_exp2f(m_run - mnew);                       \
            m_run = mnew;                                                            \
            dacc4 *= corr;                                                           \
            o0 *= corr; o1 *= corr;                                                  \
        }                                                                            \
        h8 pa0, pa1, pa2, pa3;                                                       \
        MAKE_PA(s0, pa0, pa1)                                                        \
        MAKE_PA(s1, pa2, pa3)                                                        \
        __builtin_amdgcn_s_setprio(1);                                               \
        _Pragma("unroll")                                                            \
        for (int ks = 0; ks < 4; ++ks) {                                             \
            h8 pb = (ks == 0) ? pa0 : (ks == 1) ? pa1 : (ks == 2) ? pa2 : pa3;       \
            h8 vlo = *(const h8*)(sb + bv[ks] + cur * 8192);                         \
            h8 vhi = *(const h8*)(sb + bv[ks] + cur * 8192 + 4096);                  \
            o0 = __builtin_amdgcn_mfma_f32_32x32x16_f16(vlo, pb, o0, 0, 0, 0);       \
            o1 = __builtin_amdgcn_mfma_f32_32x32x16_f16(vhi, pb, o1, 0, 0, 0);       \
        }                                                                            \
        __builtin_amdgcn_s_setprio(0);                                               \
        __syncthreads();                                                             \
    }

    for (int t2 = 0; t2 < 16; ++t2) {
        ATT_ITER(0, 2 * t2)
        ATT_ITER(1, 2 * t2 + 1)
    }
#undef ATT_ITER
#undef MAKE_PA

    float l_loc = (dacc4[0] + dacc4[1]) + (dacc4[2] + dacc4[3]);
    float l_tot = l_loc + __shfl_xor(l_loc, 32);
    float inv_l = 1.f / l_tot;
    const int token = b * 2048 + qrow;
    _Float16* aop = ao + (size_t)token * 1024 + hh * 64 + 4 * h;
    #pragma unroll
    for (int w = 0; w < 4; ++w) {
        h4 ov;
        #pragma unroll
        for (int r = 0; r < 4; ++r) ov[r] = (_Float16)(o0[w * 4 + r] * inv_l);
        *(h4*)(aop + w * 8) = ov;
    }
    #pragma unroll
    for (int w = 0; w < 4; ++w) {
        h4 ov;
        #pragma unroll
        for (int r = 0; r < 4; ++r) ov[r] = (_Float16)(o1[w * 4 + r] * inv_l);
        *(h4*)(aop + 32 + w * 8) = ov;
    }
}

// ---------------------------------------------------------------- launch

extern "C" void kernel_launch(void* const* d_in, const int* in_sizes, int n_in,
                              void* d_out, int out_size, void* d_ws, size_t ws_size,
                              hipStream_t stream) {
    const float* x   = (const float*)d_in[0];
    const int*   tq  = (const int*)d_in[1];
    const int*   tk  = (const int*)d_in[2];
    const float* Wq  = (const float*)d_in[3];
    const float* Wkv = (const float*)d_in[4];
    const float* Wo  = (const float*)d_in[5];
    const float* bo  = (const float*)d_in[6];
    float* out = (float*)d_out;

    char* ws = (char*)d_ws;
    _Float16* xh  = (_Float16*)(ws);                    //  8 MB [4096][1024]
    _Float16* w1t = (_Float16*)(ws + 8388608);          //  6 MB [3072][1024]
    _Float16* w2t = (_Float16*)(ws + 14680064);         //  2 MB [1024][1024]
    _Float16* qkv = (_Float16*)(ws + 16777216);         // 16 MB [4096][2048] (q|k)
    _Float16* vt  = (_Float16*)(ws + 33554432);         //  8 MB [32 bh][64 d][2048 n]
    _Float16* ao  = (_Float16*)(ws + 41943040);         //  8 MB [4096][1024]

    convx_kernel<<<2048, 256, 0, stream>>>(x, xh, 524288);
    transw_all_kernel<<<dim3(64, 16), 256, 0, stream>>>(Wq, Wkv, Wo, w1t, w2t);

    gemm_kernel<false><<<dim3(24, 32), 256, 0, stream>>>(xh, w1t, qkv, nullptr, vt,
                                                         4096, 3072, 1024, 2048);

    rope_kernel<<<4096, 256, 0, stream>>>(qkv, tq, tk);

    attn_kernel<<<dim3(16, 32), 256, 0, stream>>>(qkv, vt, ao);

    gemm_kernel<true><<<dim3(8, 32), 256, 0, stream>>>(ao, w2t, out, bo, nullptr,
                                                       4096, 1024, 1024, 1024);
}